// Round 8
// baseline (180.192 us; speedup 1.0000x reference)
//
#include <hip/hip_runtime.h>

typedef __bf16 bf16;
typedef __bf16 bf16x4 __attribute__((ext_vector_type(4)));
typedef __bf16 bf16x8 __attribute__((ext_vector_type(8)));
typedef float  f32x4  __attribute__((ext_vector_type(4)));

#define S_LEN 2048
#define D_DIM 1024
#define NHEAD 16
#define DHEAD 64

// ---------------------------------------------------------------------------
// async global->LDS, 16B per lane (wave-uniform LDS base + lane*16, m104).
__device__ __forceinline__ void async_cp16(const bf16* g, bf16* l) {
  __builtin_amdgcn_global_load_lds(
      (__attribute__((address_space(1))) void*)(void*)g,
      (__attribute__((address_space(3))) void*)l,
      16, 0, 0);
}

// ---------------------------------------------------------------------------
// fp32 -> bf16 cvt of x + 4 weights (blocks [0,3072)); block 3072 computes
// per-Q-tile key-block ranges kbr[0..63] and per-segment row intervals
// kbr[64..71] = {first[v], first-of-any-greater[v]} from sorted seg_ids.
__global__ __launch_bounds__(256) void cvt_k(
    const float* __restrict__ x,  const float* __restrict__ w0,
    const float* __restrict__ w1, const float* __restrict__ w2,
    const float* __restrict__ w3, bf16* __restrict__ dst,
    const int* __restrict__ seg, int* __restrict__ kbr)
{
  __shared__ int firstv[4];
  const int b = blockIdx.x;
  const int t = threadIdx.x;

  if (b < 3072) {
    int i = b * 256 + t;  // 0 .. 786431 (x8 elems)
    const float* src;
    int off;
    if (i < (1 << 18)) {            // x: 2^18 groups of 8
      src = x; off = i;
    } else {
      int j = i - (1 << 18);        // weights: 2^17 groups each
      int s = j >> 17;
      off = j & ((1 << 17) - 1);
      src = (s == 0) ? w0 : (s == 1) ? w1 : (s == 2) ? w2 : w3;
    }
    f32x4 a = *(const f32x4*)(src + (size_t)off * 8);
    f32x4 bb = *(const f32x4*)(src + (size_t)off * 8 + 4);
    bf16x8 o;
    o[0] = (bf16)a[0];  o[1] = (bf16)a[1];  o[2] = (bf16)a[2];  o[3] = (bf16)a[3];
    o[4] = (bf16)bb[0]; o[5] = (bf16)bb[1]; o[6] = (bf16)bb[2]; o[7] = (bf16)bb[3];
    *((bf16x8*)dst + i) = o;
  } else {
    if (t < 4) firstv[t] = S_LEN;
    __syncthreads();
    for (int i = t; i < S_LEN; i += 256) {
      int s = seg[i];
      if (i == 0 || seg[i - 1] != s) atomicMin(&firstv[s], i);
    }
    __syncthreads();
    if (t < 32) {
      int smin = seg[t * 64], smax = seg[t * 64 + 63];
      int lb = S_LEN, ub = S_LEN;
      for (int vv = smin; vv < 4; ++vv) lb = min(lb, firstv[vv]);
      for (int vv = smax + 1; vv < 4; ++vv) ub = min(ub, firstv[vv]);
      kbr[t * 2] = lb >> 6;
      kbr[t * 2 + 1] = (ub - 1) >> 6;  // inclusive
    }
    if (t < 4) {  // per-segment [row-begin, row-end) for attn masking
      int ubv = S_LEN;
      for (int u = t + 1; u < 4; ++u) ubv = min(ubv, firstv[u]);
      kbr[64 + t * 2] = firstv[t];
      kbr[64 + t * 2 + 1] = ubv;
    }
  }
}

// ---------------------------------------------------------------------------
// QKV GEMM (R12 — measured best): 128x64 tile, BK=128 via four split 32-k
// LDS arrays (48KB), DMA staging, 2-barrier K-loop, grid 768 = 3 blocks/CU
// exactly (grid MUST be a multiple of 256; >=2 blocks/CU — R14/R15 lesson).
// Epilogue by z: z=0 rope*0.125 -> q0; z=1 rope -> k0; z=2 transposed -> Vt.
__global__ __launch_bounds__(256) void gemm_qkv(
    const bf16* __restrict__ A,
    const bf16* __restrict__ B0, const bf16* __restrict__ B1,
    const bf16* __restrict__ B2,
    const float* __restrict__ cosT, const float* __restrict__ sinT,
    bf16* __restrict__ Cbase, bf16* __restrict__ Vt)
{
  constexpr int K = 1024, N = 1024;
  const int z = blockIdx.z;
  const bf16* W = (z == 0) ? B0 : (z == 1) ? B1 : B2;
  bf16* C = Cbase + (size_t)z * 2048 * 1024;

  __shared__ bf16 As[4][128 * 32] __attribute__((aligned(16)));  // 32KB
  __shared__ bf16 Bs[4][64 * 32] __attribute__((aligned(16)));   // 16KB

  const int t = threadIdx.x;
  const int lane = t & 63;
  const int w = t >> 6;
  const int lm = lane & 15, lq = lane >> 4;
  const int wr = w >> 1, wc = w & 1;
  const int bm = blockIdx.y, bn = blockIdx.x;

  const bf16* Abase = A + (size_t)bm * 128 * K;
  const bf16* Wbase = W + (size_t)bn * 64 * K;

  f32x4 acc[4][2] = {};

  for (int kk = 0; kk < K; kk += 128) {
#pragma unroll
    for (int kh = 0; kh < 2; ++kh)
#pragma unroll
      for (int g = 0; g < 2; ++g) {
        int c = (w * 2 + g) * 64 + lane;
        int row = c >> 2, k8 = c & 3;
        const bf16* ga = Abase + (size_t)row * K + kk + kh * 64 + k8 * 8;
        async_cp16(ga, &As[kh * 2][(w * 2 + g) * 512]);
        async_cp16(ga + 32, &As[kh * 2 + 1][(w * 2 + g) * 512]);
      }
#pragma unroll
    for (int kh = 0; kh < 2; ++kh) {
      int c = w * 64 + lane;
      int row = c >> 2, k8 = c & 3;
      const bf16* gb = Wbase + (size_t)row * K + kk + kh * 64 + k8 * 8;
      async_cp16(gb, &Bs[kh * 2][w * 512]);
      async_cp16(gb + 32, &Bs[kh * 2 + 1][w * 512]);
    }
    __syncthreads();

#pragma unroll
    for (int ks = 0; ks < 4; ++ks) {
      bf16x8 af[4], bfr[2];
#pragma unroll
      for (int mi = 0; mi < 4; ++mi)
        af[mi] = *(const bf16x8*)&As[ks][(wr * 64 + mi * 16 + lm) * 32 + lq * 8];
#pragma unroll
      for (int ni = 0; ni < 2; ++ni)
        bfr[ni] = *(const bf16x8*)&Bs[ks][(wc * 32 + ni * 16 + lm) * 32 + lq * 8];
#pragma unroll
      for (int mi = 0; mi < 4; ++mi)
#pragma unroll
        for (int ni = 0; ni < 2; ++ni)
          acc[mi][ni] = __builtin_amdgcn_mfma_f32_16x16x32_bf16(
              af[mi], bfr[ni], acc[mi][ni], 0, 0, 0);
    }
    __syncthreads();
  }

  // C/D layout: col = lane&15, row = (lane>>4)*4 + reg (m89/m91-verified)
  if (z < 2) {
    const float scale = (z == 0) ? 0.125f : 1.0f;  // 1/sqrt(DH) folded into q
#pragma unroll
    for (int mi = 0; mi < 4; ++mi)
#pragma unroll
      for (int ni = 0; ni < 2; ++ni) {
        int gcol = bn * 64 + wc * 32 + ni * 16 + lm;
        int p = (gcol & 63) >> 1;
        bool even = (gcol & 1) == 0;
#pragma unroll
        for (int r = 0; r < 4; ++r) {
          int row = bm * 128 + wr * 64 + mi * 16 + lq * 4 + r;
          float v = acc[mi][ni][r];
          float mate = __shfl_xor(v, 1);   // partner col of the rope pair
          float cv = cosT[row * 32 + p];
          float sv = sinT[row * 32 + p];
          float res = even ? (v * cv - mate * sv) : (mate * sv + v * cv);
          C[(size_t)row * N + gcol] = (bf16)(res * scale);
        }
      }
  } else {
#pragma unroll
    for (int mi = 0; mi < 4; ++mi)
#pragma unroll
      for (int ni = 0; ni < 2; ++ni) {
        int gcol = bn * 64 + wc * 32 + ni * 16 + lm;      // d index
        int rowb = bm * 128 + wr * 64 + mi * 16 + lq * 4; // s index base
        bf16x4 pack;
#pragma unroll
        for (int r = 0; r < 4; ++r) pack[r] = (bf16)acc[mi][ni][r];
        *(bf16x4*)(Vt + (size_t)gcol * S_LEN + rowb) = pack;
      }
  }
}

// ---------------------------------------------------------------------------
// Output GEMM (R12 — measured best): out = ao @ Wo^T, 64x64 tile, BK=128,
// DMA staging, 2-barrier K-loop, fp32 direct store. Grid 512 = 2 blocks/CU.
__global__ __launch_bounds__(256) void gemm_wo(
    const bf16* __restrict__ A, const bf16* __restrict__ W,
    float* __restrict__ C)
{
  constexpr int K = 1024, N = 1024;

  __shared__ bf16 As[4][64 * 32] __attribute__((aligned(16)));
  __shared__ bf16 Bs[4][64 * 32] __attribute__((aligned(16)));

  const int t = threadIdx.x;
  const int lane = t & 63;
  const int w = t >> 6;
  const int lm = lane & 15, lq = lane >> 4;
  const int bn = blockIdx.x, bm = blockIdx.y;

  const bf16* Abase = A + (size_t)bm * 64 * K;
  const bf16* Wbase = W + (size_t)bn * 64 * K;

  f32x4 acc[4] = {};

  for (int kk = 0; kk < K; kk += 128) {
#pragma unroll
    for (int kh = 0; kh < 2; ++kh) {
      int c = w * 64 + lane;
      int row = c >> 2, k8 = c & 3;
      const bf16* ga = Abase + (size_t)row * K + kk + kh * 64 + k8 * 8;
      async_cp16(ga, &As[kh * 2][w * 512]);
      async_cp16(ga + 32, &As[kh * 2 + 1][w * 512]);
      const bf16* gb = Wbase + (size_t)row * K + kk + kh * 64 + k8 * 8;
      async_cp16(gb, &Bs[kh * 2][w * 512]);
      async_cp16(gb + 32, &Bs[kh * 2 + 1][w * 512]);
    }
    __syncthreads();

#pragma unroll
    for (int ks = 0; ks < 4; ++ks) {
      bf16x8 af = *(const bf16x8*)&As[ks][(w * 16 + lm) * 32 + lq * 8];
      bf16x8 bfr[4];
#pragma unroll
      for (int ni = 0; ni < 4; ++ni)
        bfr[ni] = *(const bf16x8*)&Bs[ks][(ni * 16 + lm) * 32 + lq * 8];
#pragma unroll
      for (int ni = 0; ni < 4; ++ni)
        acc[ni] = __builtin_amdgcn_mfma_f32_16x16x32_bf16(
            af, bfr[ni], acc[ni], 0, 0, 0);
    }
    __syncthreads();
  }

#pragma unroll
  for (int ni = 0; ni < 4; ++ni) {
    int col = bn * 64 + ni * 16 + lm;
#pragma unroll
    for (int r = 0; r < 4; ++r) {
      int row = bm * 64 + w * 16 + lq * 4 + r;
      C[(size_t)row * N + col] = acc[ni][r];
    }
  }
}

// ---------------------------------------------------------------------------
// Flash attention (R17): Q-tile 128, 8 waves, NO K/V LDS staging — K/V for
// one head is 512KB, L2-resident (m169 precedent: staging L2-fit data is
// pure overhead). kf/vf MFMA fragments load directly from global with 64B-
// segment coalescing (4 lq-lanes x 16B contiguous per row). All barriers
// and segk staging gone: waves fully independent; mask via sorted-seg row
// intervals kbr[64..71] (R13-verified). LDS = per-wave Ps only (18KB).
__global__ __launch_bounds__(512, 2) void attn_k(
    const bf16* __restrict__ Q, const bf16* __restrict__ Kmat,
    const bf16* __restrict__ Vt, const int* __restrict__ seg,
    const int* __restrict__ kbr,
    bf16* __restrict__ AO)
{
  __shared__ bf16 Ps[8][16 * 72] __attribute__((aligned(16))); // per-wave P

  const int h = blockIdx.y;
  const int qt = blockIdx.x;
  const int q0 = qt * 128;
  const int t = threadIdx.x, lane = t & 63, w = t >> 6;
  const int lm = lane & 15, lq = lane >> 4;
  const int qrow = q0 + w * 16;

  const int kb0f = kbr[qt * 4], kb1f = kbr[qt * 4 + 3];  // inclusive

  bf16x8 qf[2];  // A-operand: m = lane&15, k = quad*8+j
#pragma unroll
  for (int ks = 0; ks < 2; ++ks)
    qf[ks] = *(const bf16x8*)(Q + (size_t)(qrow + lm) * D_DIM + h * DHEAD +
                              ks * 32 + lq * 8);

  int lbq[4], ubq[4];  // per-row segment key interval (sorted seg)
  float l_i[4];
#pragma unroll
  for (int r = 0; r < 4; ++r) {
    int sv = seg[qrow + lq * 4 + r];
    lbq[r] = kbr[64 + sv * 2];
    ubq[r] = kbr[64 + sv * 2 + 1];
    l_i[r] = 0.0f;
  }
  f32x4 o[4] = {};

  const bf16* Kb = Kmat + h * DHEAD;
  const bf16* Vb = Vt + (size_t)h * DHEAD * S_LEN;

  for (int kb = kb0f; kb <= kb1f; ++kb) {
    const int k0 = kb * 64;

    // S = Q K^T, kf direct from global (L2-hit)
    f32x4 sa[4] = {};
    __builtin_amdgcn_s_setprio(1);
#pragma unroll
    for (int ks = 0; ks < 2; ++ks) {
      bf16x8 kf[4];
#pragma unroll
      for (int ni = 0; ni < 4; ++ni)
        kf[ni] = *(const bf16x8*)(Kb + (size_t)(k0 + ni * 16 + lm) * D_DIM +
                                  ks * 32 + lq * 8);
#pragma unroll
      for (int ni = 0; ni < 4; ++ni)
        sa[ni] = __builtin_amdgcn_mfma_f32_16x16x32_bf16(qf[ks], kf[ni],
                                                         sa[ni], 0, 0, 0);
    }
    __builtin_amdgcn_s_setprio(0);

    // exp + interval mask; key = k0 + ni*16 + lm, row q = qrow + lq*4 + r
#pragma unroll
    for (int r = 0; r < 4; ++r)
#pragma unroll
      for (int ni = 0; ni < 4; ++ni) {
        int key = k0 + ni * 16 + lm;
        float p = (key >= lbq[r] && key < ubq[r]) ? __expf(sa[ni][r]) : 0.0f;
        l_i[r] += p;
        Ps[w][(lq * 4 + r) * 72 + ni * 16 + lm] = (bf16)p;
      }

    // O += P @ V, vf direct from global (L2-hit)
    __builtin_amdgcn_s_setprio(1);
#pragma unroll
    for (int ks = 0; ks < 2; ++ks) {
      bf16x8 pf = *(const bf16x8*)&Ps[w][lm * 72 + ks * 32 + lq * 8];
      bf16x8 vf[4];
#pragma unroll
      for (int ni = 0; ni < 4; ++ni)
        vf[ni] = *(const bf16x8*)(Vb + (size_t)(ni * 16 + lm) * S_LEN +
                                  k0 + ks * 32 + lq * 8);
#pragma unroll
      for (int ni = 0; ni < 4; ++ni)
        o[ni] = __builtin_amdgcn_mfma_f32_16x16x32_bf16(pf, vf[ni], o[ni],
                                                        0, 0, 0);
    }
    __builtin_amdgcn_s_setprio(0);
  }

  // epilogue: full denominator in-block -> normalize and store final bf16
#pragma unroll
  for (int r = 0; r < 4; ++r) {
    float l = l_i[r];
    l += __shfl_xor(l, 1);
    l += __shfl_xor(l, 2);
    l += __shfl_xor(l, 4);
    l += __shfl_xor(l, 8);
    float inv = 1.0f / l;
    int row = qrow + lq * 4 + r;
#pragma unroll
    for (int ni = 0; ni < 4; ++ni)
      AO[(size_t)row * D_DIM + h * DHEAD + ni * 16 + lm] =
          (bf16)(o[ni][r] * inv);
  }
}

// ---------------------------------------------------------------------------
extern "C" void kernel_launch(void* const* d_in, const int* in_sizes, int n_in,
                              void* d_out, int out_size, void* d_ws,
                              size_t ws_size, hipStream_t stream)
{
  const float* x  = (const float*)d_in[0];
  const int*   sg = (const int*)d_in[1];
  const float* fc = (const float*)d_in[2];
  const float* fs = (const float*)d_in[3];
  const float* wq = (const float*)d_in[4];
  const float* wk = (const float*)d_in[5];
  const float* wv = (const float*)d_in[6];
  const float* wo = (const float*)d_in[7];
  float* out = (float*)d_out;

  const size_t MAT = (size_t)S_LEN * D_DIM;  // 2M elements
  const size_t WSZ = (size_t)D_DIM * D_DIM;  // 1M elements
  bf16* xb  = (bf16*)d_ws;         // cvt_k writes xb..wob contiguous
  bf16* wqb = xb + MAT;
  bf16* wkb = wqb + WSZ;
  bf16* wvb = wkb + WSZ;
  bf16* wob = wvb + WSZ;
  bf16* q0  = wob + WSZ;           // rope'd+scaled, by gemm_qkv z=0
  bf16* k0  = q0 + MAT;            // rope'd, by gemm_qkv z=1
  bf16* vt  = k0 + MAT;            // V^T [1024][2048], by gemm_qkv z=2
  bf16* ao  = vt + MAT;            // normalized attention output (bf16)
  int*  kbr = (int*)(ao + MAT);    // 32x2 ranges + 4x2 segment intervals

  dim3 blk(256);
  cvt_k<<<dim3(3073), blk, 0, stream>>>(x, wq, wk, wv, wo, xb, sg, kbr);
  gemm_qkv<<<dim3(16, 16, 3), blk, 0, stream>>>(xb, wqb, wkb, wvb, fc, fs,
                                                q0, vt);
  attn_k<<<dim3(16, 16), dim3(512), 0, stream>>>(q0, k0, vt, sg, kbr, ao);
  gemm_wo<<<dim3(16, 32), blk, 0, stream>>>(ao, wob, out);
}

// Round 9
// 137.721 us; speedup vs baseline: 1.3084x; 1.3084x over previous
//
#include <hip/hip_runtime.h>

typedef __bf16 bf16;
typedef __bf16 bf16x4 __attribute__((ext_vector_type(4)));
typedef __bf16 bf16x8 __attribute__((ext_vector_type(8)));
typedef float  f32x4  __attribute__((ext_vector_type(4)));

#define S_LEN 2048
#define D_DIM 1024
#define NHEAD 16
#define DHEAD 64

// ---------------------------------------------------------------------------
// async global->LDS, 16B per lane (wave-uniform LDS base + lane*16, m104).
__device__ __forceinline__ void async_cp16(const bf16* g, bf16* l) {
  __builtin_amdgcn_global_load_lds(
      (__attribute__((address_space(1))) void*)(void*)g,
      (__attribute__((address_space(3))) void*)l,
      16, 0, 0);
}

// ---------------------------------------------------------------------------
// fp32 -> bf16 cvt of x + 4 weights (blocks [0,3072)); block 3072 computes
// per-Q-tile key-block ranges kbr[0..63] and per-segment row intervals
// kbr[64..71] = {first[v], first-of-any-greater[v]} from sorted seg_ids.
__global__ __launch_bounds__(256) void cvt_k(
    const float* __restrict__ x,  const float* __restrict__ w0,
    const float* __restrict__ w1, const float* __restrict__ w2,
    const float* __restrict__ w3, bf16* __restrict__ dst,
    const int* __restrict__ seg, int* __restrict__ kbr)
{
  __shared__ int firstv[4];
  const int b = blockIdx.x;
  const int t = threadIdx.x;

  if (b < 3072) {
    int i = b * 256 + t;  // 0 .. 786431 (x8 elems)
    const float* src;
    int off;
    if (i < (1 << 18)) {            // x: 2^18 groups of 8
      src = x; off = i;
    } else {
      int j = i - (1 << 18);        // weights: 2^17 groups each
      int s = j >> 17;
      off = j & ((1 << 17) - 1);
      src = (s == 0) ? w0 : (s == 1) ? w1 : (s == 2) ? w2 : w3;
    }
    f32x4 a = *(const f32x4*)(src + (size_t)off * 8);
    f32x4 bb = *(const f32x4*)(src + (size_t)off * 8 + 4);
    bf16x8 o;
    o[0] = (bf16)a[0];  o[1] = (bf16)a[1];  o[2] = (bf16)a[2];  o[3] = (bf16)a[3];
    o[4] = (bf16)bb[0]; o[5] = (bf16)bb[1]; o[6] = (bf16)bb[2]; o[7] = (bf16)bb[3];
    *((bf16x8*)dst + i) = o;
  } else {
    if (t < 4) firstv[t] = S_LEN;
    __syncthreads();
    for (int i = t; i < S_LEN; i += 256) {
      int s = seg[i];
      if (i == 0 || seg[i - 1] != s) atomicMin(&firstv[s], i);
    }
    __syncthreads();
    if (t < 32) {
      int smin = seg[t * 64], smax = seg[t * 64 + 63];
      int lb = S_LEN, ub = S_LEN;
      for (int vv = smin; vv < 4; ++vv) lb = min(lb, firstv[vv]);
      for (int vv = smax + 1; vv < 4; ++vv) ub = min(ub, firstv[vv]);
      kbr[t * 2] = lb >> 6;
      kbr[t * 2 + 1] = (ub - 1) >> 6;  // inclusive
    }
    if (t < 4) {  // per-segment [row-begin, row-end) for attn masking
      int ubv = S_LEN;
      for (int u = t + 1; u < 4; ++u) ubv = min(ubv, firstv[u]);
      kbr[64 + t * 2] = firstv[t];
      kbr[64 + t * 2 + 1] = ubv;
    }
  }
}

// ---------------------------------------------------------------------------
// QKV GEMM (R12 — measured best): 128x64 tile, BK=128 via four split 32-k
// LDS arrays (48KB), DMA staging, 2-barrier K-loop, grid 768 = 3 blocks/CU
// exactly (grid MUST be a multiple of 256; >=2 blocks/CU — R14/R15 lesson).
// Epilogue by z: z=0 rope*0.125 -> q0; z=1 rope -> k0; z=2 transposed -> Vt.
__global__ __launch_bounds__(256) void gemm_qkv(
    const bf16* __restrict__ A,
    const bf16* __restrict__ B0, const bf16* __restrict__ B1,
    const bf16* __restrict__ B2,
    const float* __restrict__ cosT, const float* __restrict__ sinT,
    bf16* __restrict__ Cbase, bf16* __restrict__ Vt)
{
  constexpr int K = 1024, N = 1024;
  const int z = blockIdx.z;
  const bf16* W = (z == 0) ? B0 : (z == 1) ? B1 : B2;
  bf16* C = Cbase + (size_t)z * 2048 * 1024;

  __shared__ bf16 As[4][128 * 32] __attribute__((aligned(16)));  // 32KB
  __shared__ bf16 Bs[4][64 * 32] __attribute__((aligned(16)));   // 16KB

  const int t = threadIdx.x;
  const int lane = t & 63;
  const int w = t >> 6;
  const int lm = lane & 15, lq = lane >> 4;
  const int wr = w >> 1, wc = w & 1;
  const int bm = blockIdx.y, bn = blockIdx.x;

  const bf16* Abase = A + (size_t)bm * 128 * K;
  const bf16* Wbase = W + (size_t)bn * 64 * K;

  f32x4 acc[4][2] = {};

  for (int kk = 0; kk < K; kk += 128) {
#pragma unroll
    for (int kh = 0; kh < 2; ++kh)
#pragma unroll
      for (int g = 0; g < 2; ++g) {
        int c = (w * 2 + g) * 64 + lane;
        int row = c >> 2, k8 = c & 3;
        const bf16* ga = Abase + (size_t)row * K + kk + kh * 64 + k8 * 8;
        async_cp16(ga, &As[kh * 2][(w * 2 + g) * 512]);
        async_cp16(ga + 32, &As[kh * 2 + 1][(w * 2 + g) * 512]);
      }
#pragma unroll
    for (int kh = 0; kh < 2; ++kh) {
      int c = w * 64 + lane;
      int row = c >> 2, k8 = c & 3;
      const bf16* gb = Wbase + (size_t)row * K + kk + kh * 64 + k8 * 8;
      async_cp16(gb, &Bs[kh * 2][w * 512]);
      async_cp16(gb + 32, &Bs[kh * 2 + 1][w * 512]);
    }
    __syncthreads();

#pragma unroll
    for (int ks = 0; ks < 4; ++ks) {
      bf16x8 af[4], bfr[2];
#pragma unroll
      for (int mi = 0; mi < 4; ++mi)
        af[mi] = *(const bf16x8*)&As[ks][(wr * 64 + mi * 16 + lm) * 32 + lq * 8];
#pragma unroll
      for (int ni = 0; ni < 2; ++ni)
        bfr[ni] = *(const bf16x8*)&Bs[ks][(wc * 32 + ni * 16 + lm) * 32 + lq * 8];
#pragma unroll
      for (int mi = 0; mi < 4; ++mi)
#pragma unroll
        for (int ni = 0; ni < 2; ++ni)
          acc[mi][ni] = __builtin_amdgcn_mfma_f32_16x16x32_bf16(
              af[mi], bfr[ni], acc[mi][ni], 0, 0, 0);
    }
    __syncthreads();
  }

  // C/D layout: col = lane&15, row = (lane>>4)*4 + reg (m89/m91-verified)
  if (z < 2) {
    const float scale = (z == 0) ? 0.125f : 1.0f;  // 1/sqrt(DH) folded into q
#pragma unroll
    for (int mi = 0; mi < 4; ++mi)
#pragma unroll
      for (int ni = 0; ni < 2; ++ni) {
        int gcol = bn * 64 + wc * 32 + ni * 16 + lm;
        int p = (gcol & 63) >> 1;
        bool even = (gcol & 1) == 0;
#pragma unroll
        for (int r = 0; r < 4; ++r) {
          int row = bm * 128 + wr * 64 + mi * 16 + lq * 4 + r;
          float v = acc[mi][ni][r];
          float mate = __shfl_xor(v, 1);   // partner col of the rope pair
          float cv = cosT[row * 32 + p];
          float sv = sinT[row * 32 + p];
          float res = even ? (v * cv - mate * sv) : (mate * sv + v * cv);
          C[(size_t)row * N + gcol] = (bf16)(res * scale);
        }
      }
  } else {
#pragma unroll
    for (int mi = 0; mi < 4; ++mi)
#pragma unroll
      for (int ni = 0; ni < 2; ++ni) {
        int gcol = bn * 64 + wc * 32 + ni * 16 + lm;      // d index
        int rowb = bm * 128 + wr * 64 + mi * 16 + lq * 4; // s index base
        bf16x4 pack;
#pragma unroll
        for (int r = 0; r < 4; ++r) pack[r] = (bf16)acc[mi][ni][r];
        *(bf16x4*)(Vt + (size_t)gcol * S_LEN + rowb) = pack;
      }
  }
}

// ---------------------------------------------------------------------------
// Output GEMM (R12 — measured best): out = ao @ Wo^T, 64x64 tile, BK=128,
// DMA staging, 2-barrier K-loop, fp32 direct store. Grid 512 = 2 blocks/CU.
__global__ __launch_bounds__(256) void gemm_wo(
    const bf16* __restrict__ A, const bf16* __restrict__ W,
    float* __restrict__ C)
{
  constexpr int K = 1024, N = 1024;

  __shared__ bf16 As[4][64 * 32] __attribute__((aligned(16)));
  __shared__ bf16 Bs[4][64 * 32] __attribute__((aligned(16)));

  const int t = threadIdx.x;
  const int lane = t & 63;
  const int w = t >> 6;
  const int lm = lane & 15, lq = lane >> 4;
  const int bn = blockIdx.x, bm = blockIdx.y;

  const bf16* Abase = A + (size_t)bm * 64 * K;
  const bf16* Wbase = W + (size_t)bn * 64 * K;

  f32x4 acc[4] = {};

  for (int kk = 0; kk < K; kk += 128) {
#pragma unroll
    for (int kh = 0; kh < 2; ++kh) {
      int c = w * 64 + lane;
      int row = c >> 2, k8 = c & 3;
      const bf16* ga = Abase + (size_t)row * K + kk + kh * 64 + k8 * 8;
      async_cp16(ga, &As[kh * 2][w * 512]);
      async_cp16(ga + 32, &As[kh * 2 + 1][w * 512]);
      const bf16* gb = Wbase + (size_t)row * K + kk + kh * 64 + k8 * 8;
      async_cp16(gb, &Bs[kh * 2][w * 512]);
      async_cp16(gb + 32, &Bs[kh * 2 + 1][w * 512]);
    }
    __syncthreads();

#pragma unroll
    for (int ks = 0; ks < 4; ++ks) {
      bf16x8 af = *(const bf16x8*)&As[ks][(w * 16 + lm) * 32 + lq * 8];
      bf16x8 bfr[4];
#pragma unroll
      for (int ni = 0; ni < 4; ++ni)
        bfr[ni] = *(const bf16x8*)&Bs[ks][(ni * 16 + lm) * 32 + lq * 8];
#pragma unroll
      for (int ni = 0; ni < 4; ++ni)
        acc[ni] = __builtin_amdgcn_mfma_f32_16x16x32_bf16(
            af, bfr[ni], acc[ni], 0, 0, 0);
    }
    __syncthreads();
  }

#pragma unroll
  for (int ni = 0; ni < 4; ++ni) {
    int col = bn * 64 + ni * 16 + lm;
#pragma unroll
    for (int r = 0; r < 4; ++r) {
      int row = bm * 64 + w * 16 + lq * 4 + r;
      C[(size_t)row * N + col] = acc[ni][r];
    }
  }
}

// ---------------------------------------------------------------------------
// Flash attention (R19 = R12 structure + swapped QK^T softmax): Q-tile 128,
// 8 waves, K/V LDS-staged with reg prefetch (R12 — proven necessary, R17).
// QK^T computed as mfma(K,Q) -> S^T: lane holds ONE q (= lm) and 16 keys,
// so the segment mask is a single per-lane interval (kbr[64..71], sorted
// seg — R13-verified), Ps writes are packed bf16x4 (4 stores vs 16 scalar),
// and l is one accumulator reduced via shfl_xor(16/32). PV unchanged.
__global__ __launch_bounds__(512, 2) void attn_k(
    const bf16* __restrict__ Q, const bf16* __restrict__ Kmat,
    const bf16* __restrict__ Vt, const int* __restrict__ seg,
    const int* __restrict__ kbr,
    bf16* __restrict__ AO)
{
  __shared__ bf16 Ks[64 * 72] __attribute__((aligned(16)));    // [key][dh]
  __shared__ bf16 Vs[64 * 72] __attribute__((aligned(16)));    // [dh][key]
  __shared__ bf16 Ps[8][16 * 72] __attribute__((aligned(16))); // per-wave P

  const int h = blockIdx.y;
  const int qt = blockIdx.x;
  const int q0 = qt * 128;
  const int t = threadIdx.x, lane = t & 63, w = t >> 6;
  const int lm = lane & 15, lq = lane >> 4;
  const int qrow = q0 + w * 16;

  const int kb0f = kbr[qt * 4], kb1f = kbr[qt * 4 + 3];  // inclusive

  bf16x8 qf[2];  // same regs serve as B-operand after the swap (n = lm = q)
#pragma unroll
  for (int ks = 0; ks < 2; ++ks)
    qf[ks] = *(const bf16x8*)(Q + (size_t)(qrow + lm) * D_DIM + h * DHEAD +
                              ks * 32 + lq * 8);

  // per-lane segment key interval for q = qrow + lm (sorted seg)
  int lb, ub;
  {
    int sv = seg[qrow + lm];
    lb = kbr[64 + sv * 2];
    ub = kbr[64 + sv * 2 + 1];
  }
  float lacc = 0.0f;
  f32x4 o[4] = {};

  const int srow0 = t >> 3, sch = (t & 7) * 8;  // 512 thr: one 16B chunk each

  f32x4 pk0, pv0;
  {
    const int k0 = kb0f * 64;
    pk0 = *(const f32x4*)(Kmat + (size_t)(k0 + srow0) * D_DIM + h * DHEAD + sch);
    pv0 = *(const f32x4*)(Vt + (size_t)(h * DHEAD + srow0) * S_LEN + k0 + sch);
  }

  for (int kb = kb0f; kb <= kb1f; ++kb) {
    __syncthreads();
    *(f32x4*)&Ks[srow0 * 72 + sch] = pk0;
    *(f32x4*)&Vs[srow0 * 72 + sch] = pv0;
    __syncthreads();

    if (kb + 1 <= kb1f) {  // prefetch next tile (uniform branch)
      const int k0 = (kb + 1) * 64;
      pk0 = *(const f32x4*)(Kmat + (size_t)(k0 + srow0) * D_DIM + h * DHEAD + sch);
      pv0 = *(const f32x4*)(Vt + (size_t)(h * DHEAD + srow0) * S_LEN + k0 + sch);
    }

    const int k0 = kb * 64;

    // S^T = K Q^T: A = K (m = key = lm-indexed), B = Q (n = q = lm).
    f32x4 sa[4] = {};
    __builtin_amdgcn_s_setprio(1);
#pragma unroll
    for (int ks = 0; ks < 2; ++ks) {
      bf16x8 kf[4];
#pragma unroll
      for (int ni = 0; ni < 4; ++ni)
        kf[ni] = *(const bf16x8*)&Ks[(ni * 16 + lm) * 72 + ks * 32 + lq * 8];
#pragma unroll
      for (int ni = 0; ni < 4; ++ni)
        sa[ni] = __builtin_amdgcn_mfma_f32_16x16x32_bf16(kf[ni], qf[ks],
                                                         sa[ni], 0, 0, 0);
    }
    __builtin_amdgcn_s_setprio(0);

    // exp + per-lane interval mask; lane q = lm, keys k0 + ni*16 + lq*4 + r
#pragma unroll
    for (int ni = 0; ni < 4; ++ni) {
      bf16x4 pk;
#pragma unroll
      for (int r = 0; r < 4; ++r) {
        int key = k0 + ni * 16 + lq * 4 + r;
        float p = (key >= lb && key < ub) ? __expf(sa[ni][r]) : 0.0f;
        lacc += p;
        pk[r] = (bf16)p;
      }
      *(bf16x4*)&Ps[w][lm * 72 + ni * 16 + lq * 4] = pk;
    }

    // O += P @ V
    __builtin_amdgcn_s_setprio(1);
#pragma unroll
    for (int ks = 0; ks < 2; ++ks) {
      bf16x8 pf = *(const bf16x8*)&Ps[w][lm * 72 + ks * 32 + lq * 8];
      bf16x8 vf[4];
#pragma unroll
      for (int ni = 0; ni < 4; ++ni)
        vf[ni] = *(const bf16x8*)&Vs[(ni * 16 + lm) * 72 + ks * 32 + lq * 8];
#pragma unroll
      for (int ni = 0; ni < 4; ++ni)
        o[ni] = __builtin_amdgcn_mfma_f32_16x16x32_bf16(pf, vf[ni], o[ni],
                                                        0, 0, 0);
    }
    __builtin_amdgcn_s_setprio(0);
  }

  // epilogue: l lives at lane q=lm; reduce over lq groups, redistribute to
  // the PV C-layout rows (q = lq*4 + r), normalize, store final bf16.
  {
    float l = lacc;
    l += __shfl_xor(l, 16);
    l += __shfl_xor(l, 32);
    float inv = 1.0f / l;
#pragma unroll
    for (int r = 0; r < 4; ++r) {
      float invr = __shfl(inv, lq * 4 + r);  // source lane s<16 holds q=s
      int row = qrow + lq * 4 + r;
#pragma unroll
      for (int ni = 0; ni < 4; ++ni)
        AO[(size_t)row * D_DIM + h * DHEAD + ni * 16 + lm] =
            (bf16)(o[ni][r] * invr);
    }
  }
}

// ---------------------------------------------------------------------------
extern "C" void kernel_launch(void* const* d_in, const int* in_sizes, int n_in,
                              void* d_out, int out_size, void* d_ws,
                              size_t ws_size, hipStream_t stream)
{
  const float* x  = (const float*)d_in[0];
  const int*   sg = (const int*)d_in[1];
  const float* fc = (const float*)d_in[2];
  const float* fs = (const float*)d_in[3];
  const float* wq = (const float*)d_in[4];
  const float* wk = (const float*)d_in[5];
  const float* wv = (const float*)d_in[6];
  const float* wo = (const float*)d_in[7];
  float* out = (float*)d_out;

  const size_t MAT = (size_t)S_LEN * D_DIM;  // 2M elements
  const size_t WSZ = (size_t)D_DIM * D_DIM;  // 1M elements
  bf16* xb  = (bf16*)d_ws;         // cvt_k writes xb..wob contiguous
  bf16* wqb = xb + MAT;
  bf16* wkb = wqb + WSZ;
  bf16* wvb = wkb + WSZ;
  bf16* wob = wvb + WSZ;
  bf16* q0  = wob + WSZ;           // rope'd+scaled, by gemm_qkv z=0
  bf16* k0  = q0 + MAT;            // rope'd, by gemm_qkv z=1
  bf16* vt  = k0 + MAT;            // V^T [1024][2048], by gemm_qkv z=2
  bf16* ao  = vt + MAT;            // normalized attention output (bf16)
  int*  kbr = (int*)(ao + MAT);    // 32x2 ranges + 4x2 segment intervals

  dim3 blk(256);
  cvt_k<<<dim3(3073), blk, 0, stream>>>(x, wq, wk, wv, wo, xb, sg, kbr);
  gemm_qkv<<<dim3(16, 16, 3), blk, 0, stream>>>(xb, wqb, wkb, wvb, fc, fs,
                                                q0, vt);
  attn_k<<<dim3(16, 16), dim3(512), 0, stream>>>(q0, k0, vt, sg, kbr, ao);
  gemm_wo<<<dim3(16, 32), blk, 0, stream>>>(ao, wob, out);
}